// Round 3
// baseline (455.166 us; speedup 1.0000x reference)
//
#include <hip/hip_runtime.h>
#include <hip/hip_bf16.h>
#include <cmath>

typedef __bf16 bf16x8 __attribute__((ext_vector_type(8)));
typedef __bf16 bf16x4 __attribute__((ext_vector_type(4)));
typedef float f32x4 __attribute__((ext_vector_type(4)));

#define GLOBAL_AS __attribute__((address_space(1)))
#define LDS_AS __attribute__((address_space(3)))

__device__ __forceinline__ void async_copy16(const void* g, void* l) {
    __builtin_amdgcn_global_load_lds((const GLOBAL_AS void*)g, (LDS_AS void*)l, 16, 0, 0);
}

#define SBAR() asm volatile("s_barrier" ::: "memory")
#define WAITLGKM0() asm volatile("s_waitcnt lgkmcnt(0)" ::: "memory")
#define WAITVM4() asm volatile("s_waitcnt vmcnt(4)" ::: "memory")
#define WAITVM0() asm volatile("s_waitcnt vmcnt(0)" ::: "memory")

// ---------------------------------------------------------------------------
// SEQ_idxes may be int64 or int32. As int32 words, int64 layout =
// [f0_lo, f0_hi(=0), ...]; int32 layout = [f0, s0(>=2049), ...]. seq[1]==0 <=> int64.
__device__ inline int get_first(const int* __restrict__ seq, int b) {
    int stride = (seq[1] == 0) ? 4 : 2;
    return seq[b * stride];
}

// ---------------------------------------------------------------------------
__global__ __launch_bounds__(256) void cast_f32_bf16(const float* __restrict__ in,
                                                     __bf16* __restrict__ out, int n4) {
    int i = blockIdx.x * 256 + threadIdx.x;
    if (i >= n4) return;
    float4 v = ((const float4*)in)[i];
    bf16x4 o;
    o[0] = (__bf16)v.x; o[1] = (__bf16)v.y; o[2] = (__bf16)v.z; o[3] = (__bf16)v.w;
    ((bf16x4*)out)[i] = o;
}

__global__ __launch_bounds__(256) void cast3_f32_bf16(
    const float* __restrict__ a, const float* __restrict__ b, const float* __restrict__ c,
    __bf16* __restrict__ oa, __bf16* __restrict__ ob, __bf16* __restrict__ oc, int n4) {
    int i = blockIdx.x * 256 + threadIdx.x;
    if (i >= n4) return;
    const float* in = (blockIdx.y == 0) ? a : (blockIdx.y == 1) ? b : c;
    __bf16* out = (blockIdx.y == 0) ? oa : (blockIdx.y == 1) ? ob : oc;
    float4 v = ((const float4*)in)[i];
    bf16x4 o;
    o[0] = (__bf16)v.x; o[1] = (__bf16)v.y; o[2] = (__bf16)v.z; o[3] = (__bf16)v.w;
    ((bf16x4*)out)[i] = o;
}

__global__ __launch_bounds__(256) void zero_f32(float* __restrict__ p, int n4) {
    int i = blockIdx.x * 256 + threadIdx.x;
    if (i < n4) ((f32x4*)p)[i] = f32x4{0.f, 0.f, 0.f, 0.f};
}

// ---------------------------------------------------------------------------
// gemm_bt: 128x128 tile, 2-barrier, residency-tuned (R2: 762 TF, 4 blocks/CU).
// Kept for the small K/V projections. EPI: 0 = bf16+bias; 1 = bf16 transposed.
template <int EPI>
__global__ __launch_bounds__(256, 4) void gemm_bt(
    const __bf16* __restrict__ A, int lda, long strideA,
    const __bf16* __restrict__ B, int ldb, long strideB,
    const float* __restrict__ bias,
    void* __restrict__ Cv, int ldc, long strideC,
    int Kfix, const int* __restrict__ seq, int exit_mode, int k_mode,
    float cs, float* __restrict__ rowsum) {
    int z = blockIdx.z;
    int m0 = blockIdx.x * 128, n0 = blockIdx.y * 128;
    int first = seq ? get_first(seq, z) : 0;
    if (exit_mode == 1 && m0 >= first) return;
    if (exit_mode == 2 && n0 >= first) return;
    int K = k_mode ? ((first + 63) & ~63) : Kfix;

    __shared__ char As[16384];
    __shared__ char Bs[16384];

    int tid = threadIdx.x;
    int lane = tid & 63, wid = tid >> 6;
    int waveM = (wid & 1) << 6, waveN = (wid >> 1) << 6;
    int quad = lane >> 4, l16 = lane & 15;

    int r0 = tid >> 3;
    int c8 = (tid & 7) ^ (r0 & 7);
    const __bf16* Ag = A + (long)z * strideA + (long)(m0 + r0) * lda + c8 * 8;
    const __bf16* Bg = B + (long)z * strideB + (long)(n0 + r0) * ldb + c8 * 8;

    f32x4 acc[4][4] = {};
    int xorv = (l16 & 7) << 4;

    for (int k0 = 0; k0 < K; k0 += 64) {
        __syncthreads();
#pragma unroll
        for (int r = 0; r < 4; ++r) {
            async_copy16(Ag + (long)(r * 32) * lda + k0, As + (tid + r * 256) * 16);
            async_copy16(Bg + (long)(r * 32) * ldb + k0, Bs + (tid + r * 256) * 16);
        }
        __syncthreads();
#pragma unroll
        for (int s = 0; s < 2; ++s) {
            int chunk = (((s << 2) + quad) << 4) ^ xorv;
            bf16x8 bfr[4];
#pragma unroll
            for (int j = 0; j < 4; ++j)
                bfr[j] = *(const bf16x8*)(Bs + (waveN + j * 16 + l16) * 128 + chunk);
#pragma unroll
            for (int i = 0; i < 4; ++i) {
                bf16x8 af = *(const bf16x8*)(As + (waveM + i * 16 + l16) * 128 + chunk);
#pragma unroll
                for (int j = 0; j < 4; ++j)
                    acc[i][j] = __builtin_amdgcn_mfma_f32_16x16x32_bf16(af, bfr[j], acc[i][j], 0, 0, 0);
            }
        }
    }

    if (EPI == 0) {
        __bf16* C = (__bf16*)Cv + (long)z * strideC;
#pragma unroll
        for (int i = 0; i < 4; ++i) {
            int rowb = m0 + waveM + i * 16 + quad * 4;
#pragma unroll
            for (int j = 0; j < 4; ++j) {
                int col = n0 + waveN + j * 16 + l16;
                float bv_ = bias[col];
#pragma unroll
                for (int r = 0; r < 4; ++r)
                    C[(long)(rowb + r) * ldc + col] = (__bf16)(acc[i][j][r] + bv_);
            }
        }
    } else {
        __bf16* C = (__bf16*)Cv + (long)z * strideC;
#pragma unroll
        for (int i = 0; i < 4; ++i) {
            int rowb = m0 + waveM + i * 16 + quad * 4;
#pragma unroll
            for (int j = 0; j < 4; ++j) {
                int col = n0 + waveN + j * 16 + l16;
                float bv_ = bias[col];
                bf16x4 o;
#pragma unroll
                for (int r = 0; r < 4; ++r) o[r] = (__bf16)(acc[i][j][r] + bv_);
                *(bf16x4*)&C[(long)col * ldc + rowb] = o;  // rowb%4==0 -> 8B aligned
            }
        }
    }
}

// ---------------------------------------------------------------------------
// mq: one MFMA quadrant (4m x 2n x 2ks = 16 MFMA), static acc indices (rule #20).
template <int MI0, int NJ0>
__device__ __forceinline__ void mq(f32x4 (&acc)[8][4], const bf16x8 (&av)[4][2],
                                   const bf16x8 (&bv)[2][2]) {
#pragma unroll
    for (int i = 0; i < 4; ++i)
#pragma unroll
        for (int j = 0; j < 2; ++j)
#pragma unroll
            for (int ks = 0; ks < 2; ++ks)
                acc[MI0 + i][NJ0 + j] = __builtin_amdgcn_mfma_f32_16x16x32_bf16(
                    av[i][ks], bv[j][ks], acc[MI0 + i][NJ0 + j], 0, 0, 0);
}

// ---------------------------------------------------------------------------
// gemm256: 256x256 tile, BK=64, 512 thr = 8 waves (2M x 4N), wave tile 128x64.
// 8-phase counted-vmcnt pipeline (T3+T4+T5), 2 K-tiles/iter, fixed buf roles:
// buf0 = even tiles (computed P1-P4), buf1 = odd tiles (P5-P8).
// Per phase: {ds_reads | stage 1 half-tile (2 gload_lds)} ; SBAR ; lgkmcnt(0) ;
// setprio(1) ; 16 MFMA ; setprio(0) ; SBAR.   NO __syncthreads (would drain vmcnt).
// Read schedule per tile: P1: A-rh0 (8 reads) + B-ch0 (4); P2: B-ch1 (4);
// P3: A-rh1 (8); P4: none.  Quadrants: P1 (rh0,ch0), P2 (rh0,ch1), P3 (rh1,ch0),
// P4 (rh1,ch1).  Frag liveness peak = 16 frags (64 VGPR) + 128 acc.
// Stage schedule (1 HT/phase; tile 2i+1 -> buf1, 2i+2 -> buf0, 2i+3 -> buf1):
//   P1: buf1.A.h1(2i+1)  P2: buf1.B.h1(2i+1)   [first halves staged P7/P8 prev]
//   P3: buf0.B.h0(2i+2)  P4: buf0.A.h0(2i+2)   (B-buf0 free after P2, A after P3)
//   P5: buf0.A.h1(2i+2)  P6: buf0.B.h1(2i+2)
//   P7: buf1.B.h0(2i+3)  P8: buf1.A.h0(2i+3)   (B-buf1 free after P6, A after P7)
// Gates (per-wave 2 loads/HT): vmcnt(4) at P4 retires {P7',P8',P1,P2} = tile 2i+1
// complete before P5 reads; vmcnt(4) at P8 retires {P3..P6} = tile 2i+2 complete
// before next P1. Stage->consume distance = 6 phases. Last iter: vmcnt(0) at P4.
// LDS XOR chunk swizzle identical to the R0-proven scheme (0 bank conflicts).
// EPI: 0 bf16+bias; 2 exp2(acc*cs) masked [1,first) + rowsum; 3 fp32 / rowsum.
// k_mode=1: K = roundup128(first) (Pb zero-padded & VT defined exactly there).
template <int EPI>
__global__ __launch_bounds__(512, 2) void gemm256(
    const __bf16* __restrict__ A, int lda, long strideA,
    const __bf16* __restrict__ B, int ldb, long strideB,
    const float* __restrict__ bias,
    void* __restrict__ Cv, int ldc, long strideC,
    int Kfix, const int* __restrict__ seq, int exit_mode, int k_mode,
    float cs, float* __restrict__ rowsum) {
    int z = blockIdx.z;
    int m0 = blockIdx.x * 256, n0 = blockIdx.y * 256;
    int first = seq ? get_first(seq, z) : 0;
    if (exit_mode == 2 && n0 >= first) return;
    int K = k_mode ? ((first + 127) & ~127) : Kfix;
    int np = K >> 7;  // iterations of 2 K-tiles

    __shared__ char As[2][32768];
    __shared__ char Bs[2][32768];

    int tid = threadIdx.x;
    int lane = tid & 63, wid = tid >> 6;
    int wrb = (wid >> 2) << 7;  // 0 / 128
    int wcb = (wid & 3) << 6;   // 0 / 64 / 128 / 192
    int quad = lane >> 4, l16 = lane & 15;
    int xr = l16 & 7;

    // staging: thread -> row rg in 64-row group, chunk slot tid&7; source chunk
    // pre-swizzled so LDS[r][c] holds global chunk c^(r&7) (linear dest).
    int rg = tid >> 3;
    int src_c8 = (tid & 7) ^ (rg & 7);
    const __bf16* Ag = A + (long)z * strideA + (long)(m0 + rg) * lda + src_c8 * 8;
    const __bf16* Bg = B + (long)z * strideB + (long)(n0 + rg) * ldb + src_c8 * 8;

#define STA(bb, h, kk) do { \
    async_copy16(Ag + (long)((h) * 128) * lda + (kk),      &As[bb][(h) * 16384 + tid * 16]); \
    async_copy16(Ag + (long)((h) * 128 + 64) * lda + (kk), &As[bb][(h) * 16384 + 8192 + tid * 16]); } while (0)
#define STB(bb, h, kk) do { \
    async_copy16(Bg + (long)((h) * 128) * ldb + (kk),      &Bs[bb][(h) * 16384 + tid * 16]); \
    async_copy16(Bg + (long)((h) * 128 + 64) * ldb + (kk), &Bs[bb][(h) * 16384 + 8192 + tid * 16]); } while (0)
#define RA(bb, row, ks) (*(const bf16x8*)(&As[bb][(row) * 128 + ((((ks) * 4 + quad) ^ xr) << 4)]))
#define RB(bb, row, ks) (*(const bf16x8*)(&Bs[bb][(row) * 128 + ((((ks) * 4 + quad) ^ xr) << 4)]))

    f32x4 acc[8][4] = {};
    bf16x8 av[4][2], b0[2][2], b1[2][2];

    // prologue: tile0 (4 HT -> buf0), tile1 first 2 HT -> buf1; gate leaves
    // tile1's 2 HTs in flight; tile0 guaranteed landed.
    STB(0, 0, 0); STA(0, 0, 0); STA(0, 1, 0); STB(0, 1, 0);
    STB(1, 0, 64); STA(1, 0, 64);
    WAITVM4();
    SBAR();

    for (int it = 0; it < np; ++it) {
        int k0 = it << 7;            // tile 2it @ k0; 2it+1 @ k0+64
        bool s2 = (it + 1) < np;     // tiles 2it+2 @ k0+128, 2it+3 @ k0+192 exist

        // ---- P1: read buf0 A-rh0 + B-ch0; stage buf1.A.h1 (tile 2it+1)
#pragma unroll
        for (int i = 0; i < 4; ++i) {
            av[i][0] = RA(0, wrb + i * 16 + l16, 0);
            av[i][1] = RA(0, wrb + i * 16 + l16, 1);
        }
#pragma unroll
        for (int j = 0; j < 2; ++j) {
            b0[j][0] = RB(0, wcb + j * 16 + l16, 0);
            b0[j][1] = RB(0, wcb + j * 16 + l16, 1);
        }
        STA(1, 1, k0 + 64);
        SBAR(); WAITLGKM0();
        __builtin_amdgcn_s_setprio(1);
        mq<0, 0>(acc, av, b0);
        __builtin_amdgcn_s_setprio(0);
        SBAR();

        // ---- P2: read buf0 B-ch1; stage buf1.B.h1 (tile 2it+1)
#pragma unroll
        for (int j = 0; j < 2; ++j) {
            b1[j][0] = RB(0, wcb + 32 + j * 16 + l16, 0);
            b1[j][1] = RB(0, wcb + 32 + j * 16 + l16, 1);
        }
        STB(1, 1, k0 + 64);
        SBAR(); WAITLGKM0();
        __builtin_amdgcn_s_setprio(1);
        mq<0, 2>(acc, av, b1);
        __builtin_amdgcn_s_setprio(0);
        SBAR();

        // ---- P3: read buf0 A-rh1; stage buf0.B.h0 (tile 2it+2)
#pragma unroll
        for (int i = 0; i < 4; ++i) {
            av[i][0] = RA(0, wrb + 64 + i * 16 + l16, 0);
            av[i][1] = RA(0, wrb + 64 + i * 16 + l16, 1);
        }
        if (s2) STB(0, 0, k0 + 128);
        SBAR(); WAITLGKM0();
        __builtin_amdgcn_s_setprio(1);
        mq<4, 0>(acc, av, b0);
        __builtin_amdgcn_s_setprio(0);
        SBAR();

        // ---- P4: stage buf0.A.h0 (tile 2it+2); GATE tile 2it+1
        if (s2) {
            STA(0, 0, k0 + 128);
            WAITVM4();
        } else {
            WAITVM0();
        }
        SBAR();
        __builtin_amdgcn_s_setprio(1);
        mq<4, 2>(acc, av, b1);
        __builtin_amdgcn_s_setprio(0);
        SBAR();

        // ---- P5: read buf1 A-rh0 + B-ch0; stage buf0.A.h1 (tile 2it+2)
#pragma unroll
        for (int i = 0; i < 4; ++i) {
            av[i][0] = RA(1, wrb + i * 16 + l16, 0);
            av[i][1] = RA(1, wrb + i * 16 + l16, 1);
        }
#pragma unroll
        for (int j = 0; j < 2; ++j) {
            b0[j][0] = RB(1, wcb + j * 16 + l16, 0);
            b0[j][1] = RB(1, wcb + j * 16 + l16, 1);
        }
        if (s2) STA(0, 1, k0 + 128);
        SBAR(); WAITLGKM0();
        __builtin_amdgcn_s_setprio(1);
        mq<0, 0>(acc, av, b0);
        __builtin_amdgcn_s_setprio(0);
        SBAR();

        // ---- P6: read buf1 B-ch1; stage buf0.B.h1 (tile 2it+2)
#pragma unroll
        for (int j = 0; j < 2; ++j) {
            b1[j][0] = RB(1, wcb + 32 + j * 16 + l16, 0);
            b1[j][1] = RB(1, wcb + 32 + j * 16 + l16, 1);
        }
        if (s2) STB(0, 1, k0 + 128);
        SBAR(); WAITLGKM0();
        __builtin_amdgcn_s_setprio(1);
        mq<0, 2>(acc, av, b1);
        __builtin_amdgcn_s_setprio(0);
        SBAR();

        // ---- P7: read buf1 A-rh1; stage buf1.B.h0 (tile 2it+3)
#pragma unroll
        for (int i = 0; i < 4; ++i) {
            av[i][0] = RA(1, wrb + 64 + i * 16 + l16, 0);
            av[i][1] = RA(1, wrb + 64 + i * 16 + l16, 1);
        }
        if (s2) STB(1, 0, k0 + 192);
        SBAR(); WAITLGKM0();
        __builtin_amdgcn_s_setprio(1);
        mq<4, 0>(acc, av, b0);
        __builtin_amdgcn_s_setprio(0);
        SBAR();

        // ---- P8: stage buf1.A.h0 (tile 2it+3); GATE tile 2it+2
        if (s2) {
            STA(1, 0, k0 + 192);
            WAITVM4();
        }
        SBAR();
        __builtin_amdgcn_s_setprio(1);
        mq<4, 2>(acc, av, b1);
        __builtin_amdgcn_s_setprio(0);
        SBAR();
    }
#undef STA
#undef STB
#undef RA
#undef RB

    // C/D frag: col = l16 (n), row = quad*4 + reg (m). [m89-verified]
    if (EPI == 0) {
        __bf16* C = (__bf16*)Cv + (long)z * strideC;
#pragma unroll
        for (int i = 0; i < 8; ++i) {
            int rowb = m0 + wrb + i * 16 + quad * 4;
#pragma unroll
            for (int j = 0; j < 4; ++j) {
                int col = n0 + wcb + j * 16 + l16;
                float bv_ = bias[col];
#pragma unroll
                for (int r = 0; r < 4; ++r)
                    C[(long)(rowb + r) * ldc + col] = (__bf16)(acc[i][j][r] + bv_);
            }
        }
    } else if (EPI == 2) {
        __bf16* C = (__bf16*)Cv + (long)z * strideC;
        float* rs = rowsum + (long)z * 4096;
#pragma unroll
        for (int i = 0; i < 8; ++i) {
            int rowb = m0 + wrb + i * 16 + quad * 4;
            float sum[4] = {0.f, 0.f, 0.f, 0.f};
#pragma unroll
            for (int j = 0; j < 4; ++j) {
                int col = n0 + wcb + j * 16 + l16;
                bool valid = (col >= 1) && (col < first);
#pragma unroll
                for (int r = 0; r < 4; ++r) {
                    float e = valid ? exp2f(acc[i][j][r] * cs) : 0.0f;
                    __bf16 pb = (__bf16)e;
                    C[(long)(rowb + r) * ldc + col] = pb;
                    sum[r] += (float)pb;  // sum the bf16-rounded value (consistent w/ PV)
                }
            }
#pragma unroll
            for (int r = 0; r < 4; ++r) {
                float v = sum[r];
                v += __shfl_xor(v, 8); v += __shfl_xor(v, 4);
                v += __shfl_xor(v, 2); v += __shfl_xor(v, 1);
                if (l16 == 0) atomicAdd(&rs[rowb + r], v);
            }
        }
    } else {
        float* C = (float*)Cv + (long)z * strideC;
        const float* rs = rowsum + (long)z * 4096;
#pragma unroll
        for (int i = 0; i < 8; ++i) {
            int rowb = m0 + wrb + i * 16 + quad * 4;
            float inv[4];
#pragma unroll
            for (int r = 0; r < 4; ++r) inv[r] = 1.0f / rs[rowb + r];
#pragma unroll
            for (int j = 0; j < 4; ++j) {
                int col = n0 + wcb + j * 16 + l16;
#pragma unroll
                for (int r = 0; r < 4; ++r)
                    C[(long)(rowb + r) * ldc + col] = acc[i][j][r] * inv[r];
            }
        }
    }
}

// ---------------------------------------------------------------------------
extern "C" void kernel_launch(void* const* d_in, const int* in_sizes, int n_in,
                              void* d_out, int out_size, void* d_ws, size_t ws_size,
                              hipStream_t stream) {
    const int B = 8, S = 4096, E = 768, SK = 2048;
    const float* ebd  = (const float*)d_in[0];
    const int*   seq  = (const int*)d_in[1];
    const float* Wq_w = (const float*)d_in[2];
    const float* Wq_b = (const float*)d_in[3];
    const float* Wk_w = (const float*)d_in[4];
    const float* Wk_b = (const float*)d_in[5];
    const float* Wv_w = (const float*)d_in[6];
    const float* Wv_b = (const float*)d_in[7];
    float* out = (float*)d_out;

    char* p = (char*)d_ws;
    __bf16* ebd_bf = (__bf16*)p; p += (size_t)B * S * E * 2;   // 50.3 MB
    __bf16* wq = (__bf16*)p;     p += (size_t)E * E * 2;
    __bf16* wk = (__bf16*)p;     p += (size_t)E * E * 2;
    __bf16* wv = (__bf16*)p;     p += (size_t)E * E * 2;
    __bf16* Qb = (__bf16*)p;     p += (size_t)B * S * E * 2;   // 50.3 MB
    __bf16* Kb = (__bf16*)p;     p += (size_t)B * SK * E * 2;  // 25.2 MB
    __bf16* VT = (__bf16*)p;     p += (size_t)B * E * SK * 2;  // 25.2 MB  V^T: [b][e][k]
    __bf16* Pb = (__bf16*)p;     p += (size_t)B * S * SK * 2;  // 134.2 MB exp-scores
    float* rowsum = (float*)p;   p += (size_t)B * S * 4;       // 128 KB

    zero_f32<<<B * S / 4 / 256, 256, 0, stream>>>(rowsum, B * S / 4);
    cast_f32_bf16<<<(B * S * E / 4 + 255) / 256, 256, 0, stream>>>(ebd, ebd_bf, B * S * E / 4);
    cast3_f32_bf16<<<dim3((E * E / 4 + 255) / 256, 3), 256, 0, stream>>>(
        Wq_w, Wk_w, Wv_w, wq, wk, wv, E * E / 4);

    float cs = (1.0f / sqrtf((float)E)) * 1.44269504088896f;  // scale * log2(e)

    // Q = ebd @ Wq^T + bq  (M = B*S as one GEMM) [256² 8-phase]
    gemm256<0><<<dim3(B * S / 256, E / 256, 1), 512, 0, stream>>>(
        ebd_bf, E, 0, wq, E, 0, Wq_b, Qb, E, 0, E, nullptr, 0, 0, 0.f, nullptr);
    // K[b] = ebd[b,0:2048] @ Wk^T + bk  (skip m-tiles >= first) [128²]
    gemm_bt<0><<<dim3(SK / 128, E / 128, B), 256, 0, stream>>>(
        ebd_bf, E, (long)S * E, wk, E, 0, Wk_b, Kb, E, (long)SK * E, E, seq, 1, 0, 0.f, nullptr);
    // VT[b] = (ebd[b,0:2048] @ Wv^T + bv)^T [128²]
    gemm_bt<1><<<dim3(SK / 128, E / 128, B), 256, 0, stream>>>(
        ebd_bf, E, (long)S * E, wv, E, 0, Wv_b, VT, SK, (long)E * SK, E, seq, 1, 0, 0.f, nullptr);
    // P[b] = exp(Q K^T * scale) masked to [1,first), + rowsum atomics [256² 8-phase]
    gemm256<2><<<dim3(S / 256, SK / 256, B), 512, 0, stream>>>(
        Qb, E, (long)S * E, Kb, E, (long)SK * E, nullptr, Pb, SK, (long)S * SK, E, seq, 2, 0, cs, rowsum);
    // out[b] = (P[b] @ V[b]) / rowsum  (K = roundup128(first)) [256² 8-phase]
    gemm256<3><<<dim3(S / 256, E / 256, B), 512, 0, stream>>>(
        Pb, SK, (long)S * SK, VT, SK, (long)E * SK, nullptr, out, E, (long)S * E, 0, seq, 0, 1, 0.f, rowsum);
}